// Round 8
// baseline (166.153 us; speedup 1.0000x reference)
//
#include <hip/hip_runtime.h>

// B=8, S=2048, IN=1024, H=1024
//   q  = vec @ wq_w^T + wq_b            [B,S,H]
//   ret= relu(q_b^T q_b) per batch      [B,H,H]   (registers only)
//   out= ret @ lin_w + lin_b            [B,H]
//
// Pipeline:
//   prep:       out init + vec/wq fp32->bf16 (XCD-aligned vec remap, r7).
//   gemm_2b:    256x128 tile, BK=32, 48 KiB LDS -> 2 blocks/CU. Each block
//               runs syrk's proven dbuf 2-phase counted-vmcnt loop; the TWO
//               independent barrier groups per CU overlap LDS-read bursts
//               with MFMA bursts (cross-block pipe overlap, hang-free).
//   syrk_half8: fp8, BK=128, dbuf 2-phase counted-vmcnt, batch->XCD swizzle.
//
// Hard-won constraints (rounds 0-7):
//   - ALL LDS staging via global_load_lds (ds_write staging => 2.26M bank
//     conflicts, -55%; r3).
//   - Single-barrier-group schedules are pinned at 43-45 us / 28% MfmaUtil
//     regardless of phase count, vmcnt distance, XCD swizzle, producer
//     alignment (r0-r4, r7): LDS and MFMA bursts serialize at the barriers.
//   - Intra-block de-sync (no per-tile barrier) hung the container (r5/r6).
//   - relu nonlinear -> syrk K-split across blocks illegal; full K per block.
//   - 16B-granular LDS swizzle: XOR with bits ABOVE the 128B bank period
//     ((row>>1)&3 for 64B rows), not (row&3), else 4-way conflicts.

typedef short     bf16x8 __attribute__((ext_vector_type(8)));
typedef unsigned short u16x8 __attribute__((ext_vector_type(8)));
typedef float     f32x4 __attribute__((ext_vector_type(4)));
typedef long long i64;

#define FENCE asm volatile("" ::: "memory")
#define BARR  do { FENCE; __builtin_amdgcn_s_barrier(); FENCE; } while (0)
#define VMCNT(N) asm volatile("s_waitcnt vmcnt(" #N ")" ::: "memory")

__device__ inline unsigned short f2bf(float f) {
  unsigned int u = __float_as_uint(f);
  u += 0x7fffu + ((u >> 16) & 1u);   // RNE
  return (unsigned short)(u >> 16);
}

__device__ inline u16x8 pack8(float4 a, float4 b) {
  u16x8 r;
  r[0] = f2bf(a.x); r[1] = f2bf(a.y); r[2] = f2bf(a.z); r[3] = f2bf(a.w);
  r[4] = f2bf(b.x); r[5] = f2bf(b.y); r[6] = f2bf(b.z); r[7] = f2bf(b.w);
  return r;
}

__device__ inline unsigned char f2fp8(float v) {
  int pk = __builtin_amdgcn_cvt_pk_fp8_f32(v, v, 0, false);  // RNE, OCP e4m3
  return (unsigned char)(pk & 0xff);
}

__device__ inline void async16(void* lds, const void* g) {
  __builtin_amdgcn_global_load_lds(
      (const __attribute__((address_space(1))) void*)g,
      (__attribute__((address_space(3))) void*)lds,
      16, 0, 0);
}

// One launch: vec cvt (blocks 0..8191, XCD-aligned), wq cvt, out init.
__global__ __launch_bounds__(256) void prep(
    const float* __restrict__ vec, unsigned short* __restrict__ vecbf,
    const float* __restrict__ wq,  unsigned short* __restrict__ wqbf,
    const float* __restrict__ lin_b, float* __restrict__ out)
{
  if (blockIdx.x < 8192) {
    const int c   = ((blockIdx.x & 7) << 10) + (blockIdx.x >> 3);  // 0..8191
    const int gid = c * 256 + threadIdx.x;
    const float4* s = (const float4*)(vec + (size_t)gid * 8);
    float4 a = s[0], b = s[1];
    *(u16x8*)(vecbf + (size_t)gid * 8) = pack8(a, b);
    const int oid = blockIdx.x * 256 + threadIdx.x;
    if (oid < 8192) out[oid] = lin_b[0];
  } else {
    const int i = (blockIdx.x - 8192) * 256 + threadIdx.x;   // 0..131071
    const float4* s = (const float4*)(wq + (size_t)i * 8);
    float4 a = s[0], b = s[1];
    *(u16x8*)(wqbf + (size_t)i * 8) = pack8(a, b);
  }
}

__global__ void init_out(float* __restrict__ out, const float* __restrict__ lin_b) {
  int i = blockIdx.x * 256 + threadIdx.x;
  if (i < 8192) out[i] = lin_b[0];
}

// ------- gemm_2b: 256x128 tile, BK=32, 2 blocks/CU, dbuf 2-phase -------
// C[m][n] = sum_k A[m][k]*B[n][k];  A=wqbf [1024,1024], B=vecbf [16384,1024].
// 256 thr = 4 waves (2M x 2N); wave tile 128x64 (8x4 16x16 frags).
// LDS: (A 256x32 + B 128x32) bf16 x 2 slots = 48 KiB -> 2 blocks/CU.
// Per K-tile: stage(kt+1 -> other slot) BEFORE compute(kt); VMCNT(6)+BARR
// before reads (6 = next tile's insts in flight). Two co-resident blocks'
// phases are mutually unsynchronized -> LDS bursts overlap MFMA bursts.
// Swizzle: 4 chunks/row (16 B); slot c holds global chunk c ^ ((row>>1)&3)
// -> frag read (chunk=quad) lands exactly 2-way per bank (free, m136).
__global__ __launch_bounds__(256, 2) void gemm_2b(
    const unsigned short* __restrict__ A, const unsigned short* __restrict__ Bm,
    const float* __restrict__ bias, unsigned char* __restrict__ qT8)
{
  __shared__ unsigned short As[2][256 * 32];   // 32 KiB
  __shared__ unsigned short Bs[2][128 * 32];   // 16 KiB

  const int n0 = blockIdx.x * 128;   // 128 n-tiles
  const int m0 = blockIdx.y * 256;   // 4 m-tiles

  const int t    = threadIdx.x;          // 0..255
  const int lane = t & 63;
  const int wave = t >> 6;               // 0..3
  const int wm   = (wave >> 1) * 128;    // 0,128
  const int wn   = (wave & 1) * 64;      // 0,64
  const int quad = lane >> 4;
  const int lrow = lane & 15;

  // staging: thread t covers row (t>>2) of each 64-row group, chunk t&3
  // (16 B). Global chunk pre-swizzled: (t&3) ^ ((srow>>1)&3); issue stride
  // 64 rows keeps (row>>1)&3 invariant across p.
  const int srow = t >> 2;                         // 0..63
  const int gch  = (t & 3) ^ ((srow >> 1) & 3);
  const unsigned short* gA = A  + (size_t)(m0 + srow) * 1024 + gch * 8;
  const unsigned short* gB = Bm + (size_t)(n0 + srow) * 1024 + gch * 8;

  // per-thread LDS byte offset within a slot = 16*t  (+ p*4096 B per issue)
#define GSTAGE(SLOT, KT) do { \
  _Pragma("unroll") for (int p = 0; p < 4; ++p) \
    async16(&As[SLOT][p * 2048 + t * 8], gA + (size_t)p * 64 * 1024 + (KT) * 32); \
  _Pragma("unroll") for (int p = 0; p < 2; ++p) \
    async16(&Bs[SLOT][p * 2048 + t * 8], gB + (size_t)p * 64 * 1024 + (KT) * 32); \
} while (0)

  // fragment read: row r, want global chunk=quad -> slot quad ^ ((r>>1)&3)
#define GCOMPUTE(S) do { \
  bf16x8 af[8], bfr[4]; \
  _Pragma("unroll") for (int f = 0; f < 8; ++f) { \
    const int r = wm + f * 16 + lrow; \
    af[f] = *(const bf16x8*)&As[S][r * 32 + ((quad ^ ((r >> 1) & 3)) * 8)]; \
  } \
  _Pragma("unroll") for (int g = 0; g < 4; ++g) { \
    const int r = wn + g * 16 + lrow; \
    bfr[g] = *(const bf16x8*)&Bs[S][r * 32 + ((quad ^ ((r >> 1) & 3)) * 8)]; \
  } \
  __builtin_amdgcn_s_setprio(1); \
  _Pragma("unroll") for (int f = 0; f < 8; ++f) \
  _Pragma("unroll") for (int g = 0; g < 4; ++g) \
    acc[f][g] = __builtin_amdgcn_mfma_f32_16x16x32_bf16(af[f], bfr[g], acc[f][g], 0, 0, 0); \
  __builtin_amdgcn_s_setprio(0); \
} while (0)

  f32x4 acc[8][4];
#pragma unroll
  for (int f = 0; f < 8; ++f)
#pragma unroll
    for (int g = 0; g < 4; ++g) acc[f][g] = (f32x4){0.f, 0.f, 0.f, 0.f};

  // prologue: stage tile 0 -> slot 0 (6 insts outstanding)
  GSTAGE(0, 0);

#pragma unroll 1
  for (int kt = 0; kt < 31; ++kt) {
    const int s = kt & 1;
    GSTAGE(s ^ 1, kt + 1);   // 6 insts; tile kt's 6 may still be in flight
    VMCNT(6);                // completes tile kt, leaves tile kt+1 in flight
    BARR;                    // all waves' tile-kt stages now visible
    GCOMPUTE(s);
    BARR;                    // reads done before next iter overwrites slot s
  }

  // peeled kt=31 (slot 1): drain
  VMCNT(0);
  BARR;
  GCOMPUTE(1);

#undef GSTAGE
#undef GCOMPUTE

  // ---- epilogue: bias + fp8 quantize, write qT8[m][n] ----
#pragma unroll
  for (int f = 0; f < 8; ++f)
#pragma unroll
    for (int r = 0; r < 4; ++r) {
      const int m = m0 + wm + f * 16 + quad * 4 + r;
      const float bv = bias[m];
      unsigned char* row = qT8 + (size_t)m * 16384 + n0 + wn;
#pragma unroll
      for (int g = 0; g < 4; ++g)
        row[g * 16 + lrow] = f2fp8(acc[f][g][r] + bv);
    }
}

// ------- fallback gemm_q (fused fp32->bf16 inline), used if ws too small -------
__global__ __launch_bounds__(256) void gemm_q_fused(
    const float* __restrict__ Wq, const float* __restrict__ V,
    const float* __restrict__ bias, unsigned char* __restrict__ qT8)
{
  __shared__ unsigned short As[128 * 32];
  __shared__ unsigned short Bs[128 * 32];

  const int m0 = blockIdx.y * 128;
  const int n0 = blockIdx.x * 128;
  const int t    = threadIdx.x;
  const int lane = t & 63;
  const int wave = t >> 6;
  const int wm = (wave >> 1) * 64;
  const int wn = (wave & 1) * 64;
  const int quad = lane >> 4;
  const int lrow = lane & 15;

  const int sr = t >> 1;
  const int sc = (t & 1) << 4;
  const float* gA = Wq + (size_t)(m0 + sr) * 1024 + sc;
  const float* gB = V  + (size_t)(n0 + sr) * 1024 + sc;

  f32x4 acc[4][4];
#pragma unroll
  for (int i = 0; i < 4; ++i)
#pragma unroll
    for (int j = 0; j < 4; ++j) acc[i][j] = (f32x4){0.f, 0.f, 0.f, 0.f};

  for (int k0 = 0; k0 < 1024; k0 += 32) {
    const float4* a4 = (const float4*)(gA + k0);
    const float4* b4 = (const float4*)(gB + k0);
    float4 av0 = a4[0], av1 = a4[1], av2 = a4[2], av3 = a4[3];
    float4 bv0 = b4[0], bv1 = b4[1], bv2 = b4[2], bv3 = b4[3];
    *(u16x8*)&As[sr * 32 + sc]     = pack8(av0, av1);
    *(u16x8*)&As[sr * 32 + sc + 8] = pack8(av2, av3);
    *(u16x8*)&Bs[sr * 32 + sc]     = pack8(bv0, bv1);
    *(u16x8*)&Bs[sr * 32 + sc + 8] = pack8(bv2, bv3);
    __syncthreads();

    bf16x8 af[4], bfr[4];
#pragma unroll
    for (int i = 0; i < 4; ++i)
      af[i] = *(const bf16x8*)&As[(wm + i * 16 + lrow) * 32 + quad * 8];
#pragma unroll
    for (int j = 0; j < 4; ++j)
      bfr[j] = *(const bf16x8*)&Bs[(wn + j * 16 + lrow) * 32 + quad * 8];
#pragma unroll
    for (int i = 0; i < 4; ++i)
#pragma unroll
      for (int j = 0; j < 4; ++j)
        acc[i][j] = __builtin_amdgcn_mfma_f32_16x16x32_bf16(af[i], bfr[j], acc[i][j], 0, 0, 0);
    __syncthreads();
  }

#pragma unroll
  for (int i = 0; i < 4; ++i) {
    const int mb = m0 + wm + i * 16 + quad * 4;
#pragma unroll
    for (int r = 0; r < 4; ++r) {
      const float bv = bias[mb + r];
#pragma unroll
      for (int j = 0; j < 4; ++j) {
        const int n = n0 + wn + j * 16 + lrow;
        qT8[(size_t)(mb + r) * 16384 + n] = f2fp8(acc[i][j][r] + bv);
      }
    }
  }
}

// ---------- syrk_half8: fp8, BK=128, dbuf 2-phase, batch->XCD swizzle ----------
// qT8 fp8 [1024][16384]; batch bb cols [bb*2048,+2048) = 2 MiB -> fits ONE
// XCD's 4 MiB L2. blockIdx.x in [0,576): bb = bid&7 so all 72 blocks of batch
// bb land on XCD bb -> after warmup all qT8 reads are L2 hits.
// id2=bid>>3: pair=id2>>1 (ty<=tx over 8 128-tiles), yh=id2&1.
// FULL K=2048 (relu nonlinear -> K-split illegal).
__global__ __launch_bounds__(256) void syrk_half8(
    const unsigned char* __restrict__ qT8, const float* __restrict__ W,
    float* __restrict__ out)
{
  __shared__ unsigned char As[2][128 * 128];  // 32 KB
  __shared__ unsigned char Bs[2][64 * 128];   // 16 KB

  const int bb   = blockIdx.x & 7;
  const int id2  = blockIdx.x >> 3;           // 0..71
  const int pair = id2 >> 1;
  const int yh   = id2 & 1;
  int tx = 0;
  while ((tx + 1) * (tx + 2) / 2 <= pair) ++tx;
  const int ty = pair - tx * (tx + 1) / 2;
  const int x0 = tx * 128;
  const int y0 = ty * 128 + yh * 64;
  const bool diag = (tx == ty);

  const int t    = threadIdx.x;
  const int lane = t & 63;
  const int wave = t >> 6;
  const int wm = (wave >> 1) * 64;   // x offset of wave: 0 or 64
  const int wn = (wave & 1) * 32;    // y offset of wave: 0 or 32
  const int quad = lane >> 4;
  const int lrow = lane & 15;

  // staging: issue p covers rows p*32 + (t>>3); global 16B chunk
  // (t&7)^(row&7) lands at LDS slot t&7.
  const int srow = t >> 3;                              // 0..31
  const int g16  = (t & 7) ^ (srow & 7);
  const size_t cb = (size_t)bb * 2048 + g16 * 16;
  const unsigned char* gA = qT8 + (size_t)(x0 + srow) * 16384 + cb;
  const unsigned char* gB = qT8 + (size_t)(y0 + srow) * 16384 + cb;

#define SSTAGE(SLOT, KT) do { \
  _Pragma("unroll") for (int p = 0; p < 4; ++p) \
    async16(&As[SLOT][p * 4096 + t * 16], gA + (size_t)p * 32 * 16384 + (KT) * 128); \
  _Pragma("unroll") for (int p = 0; p < 2; ++p) \
    async16(&Bs[SLOT][p * 4096 + t * 16], gB + (size_t)p * 32 * 16384 + (KT) * 128); \
} while (0)

#define SYRK_COMPUTE(S) do { \
  _Pragma("unroll") for (int kk = 0; kk < 4; ++kk) { \
    const int c = kk * 4 + quad; \
    const int off = (((c >> 1) ^ (lrow & 7)) << 4) + (c & 1) * 8; \
    i64 af[4], bfr[2]; \
    _Pragma("unroll") for (int i = 0; i < 4; ++i) \
      af[i] = *(const i64*)&As[S][(wm + i * 16 + lrow) * 128 + off]; \
    _Pragma("unroll") for (int j = 0; j < 2; ++j) \
      bfr[j] = *(const i64*)&Bs[S][(wn + j * 16 + lrow) * 128 + off]; \
    _Pragma("unroll") for (int i = 0; i < 4; ++i) \
      _Pragma("unroll") for (int j = 0; j < 2; ++j) \
        acc[i][j] = __builtin_amdgcn_mfma_f32_16x16x32_fp8_fp8(af[i], bfr[j], acc[i][j], 0, 0, 0); \
  } \
} while (0)

  f32x4 acc[4][2];
#pragma unroll
  for (int i = 0; i < 4; ++i)
#pragma unroll
    for (int j = 0; j < 2; ++j) acc[i][j] = (f32x4){0.f, 0.f, 0.f, 0.f};

  // prologue: stage tile 0 -> slot 0 (6 insts outstanding)
  SSTAGE(0, 0);

#pragma unroll 1
  for (int kt = 0; kt < 15; ++kt) {
    const int s = kt & 1;
    SSTAGE(s ^ 1, kt + 1);   // 6 insts; tile t's 6 may still be in flight
    VMCNT(6);                // completes tile t, leaves tile t+1 in flight
    BARR;                    // all waves' tile-t stages now visible
    SYRK_COMPUTE(s);
    BARR;                    // reads done before next iter overwrites slot s
  }

  // peeled kt=15 (slot 1): drain
  VMCNT(0);
  BARR;
  SYRK_COMPUTE(1);

#undef SSTAGE
#undef SYRK_COMPUTE

  float* ob = out + bb * 1024;

  // row pass: out[x] += sum_y relu(C[x,y]) * W[y]   (partial over this y-half)
  float wv[2];
#pragma unroll
  for (int j = 0; j < 2; ++j) wv[j] = W[y0 + wn + j * 16 + lrow];

#pragma unroll
  for (int i = 0; i < 4; ++i) {
#pragma unroll
    for (int r = 0; r < 4; ++r) {
      float p = 0.f;
#pragma unroll
      for (int j = 0; j < 2; ++j) {
        float v = acc[i][j][r];
        v = v > 0.f ? v : 0.f;
        p += v * wv[j];
      }
#pragma unroll
      for (int off = 1; off < 16; off <<= 1) p += __shfl_xor(p, off, 64);
      if (lrow == 0)
        atomicAdd(&ob[x0 + wm + i * 16 + quad * 4 + r], p);
    }
  }

  // col pass (off-diagonal pairs only): out[y] += sum_x relu(C[x,y]) * W[x]
  if (!diag) {
    float wx[4][4];
#pragma unroll
    for (int i = 0; i < 4; ++i)
#pragma unroll
      for (int r = 0; r < 4; ++r)
        wx[i][r] = W[x0 + wm + i * 16 + quad * 4 + r];

#pragma unroll
    for (int j = 0; j < 2; ++j) {
      float pc = 0.f;
#pragma unroll
      for (int i = 0; i < 4; ++i)
#pragma unroll
        for (int r = 0; r < 4; ++r) {
          float v = acc[i][j][r];
          v = v > 0.f ? v : 0.f;
          pc += v * wx[i][r];
        }
      pc += __shfl_xor(pc, 16, 64);
      pc += __shfl_xor(pc, 32, 64);
      if (quad == 0)
        atomicAdd(&ob[y0 + wn + j * 16 + lrow], pc);
    }
  }
}

extern "C" void kernel_launch(void* const* d_in, const int* in_sizes, int n_in,
                              void* d_out, int out_size, void* d_ws, size_t ws_size,
                              hipStream_t stream) {
  const float* vec   = (const float*)d_in[0];  // [8,2048,1024]
  const float* wq_w  = (const float*)d_in[1];  // [1024,1024]
  const float* wq_b  = (const float*)d_in[2];  // [1024]
  const float* lin_w = (const float*)d_in[3];  // [1,1024]
  const float* lin_b = (const float*)d_in[4];  // [1]
  float* out = (float*)d_out;                  // [8,1024]

  unsigned char* qT8 = (unsigned char*)d_ws;                       // 16 MiB
  const size_t need = (size_t)(16 + 32 + 2) * 1024 * 1024;

  if (ws_size >= need) {
    unsigned short* vecbf = (unsigned short*)((char*)d_ws + (size_t)16 * 1024 * 1024); // 32 MiB
    unsigned short* wqbf  = vecbf + (size_t)16 * 1024 * 1024;                          // 2 MiB
    prep<<<dim3(8192 + 512), dim3(256), 0, stream>>>(vec, vecbf, wq_w, wqbf, lin_b, out);
    gemm_2b<<<dim3(128, 4), dim3(256), 0, stream>>>(wqbf, vecbf, wq_b, qT8);
  } else {
    init_out<<<dim3(32), dim3(256), 0, stream>>>(out, lin_b);
    gemm_q_fused<<<dim3(128, 8), dim3(256), 0, stream>>>(wq_w, vec, wq_b, qT8);
  }
  syrk_half8<<<dim3(576), dim3(256), 0, stream>>>(qT8, lin_w, out);
}

// Round 9
// 165.605 us; speedup vs baseline: 1.0033x; 1.0033x over previous
//
#include <hip/hip_runtime.h>

// B=8, S=2048, IN=1024, H=1024
//   q  = vec @ wq_w^T + wq_b            [B,S,H]
//   ret= relu(q_b^T q_b) per batch      [B,H,H]   (registers only)
//   out= ret @ lin_w + lin_b            [B,H]
//
// Pipeline:
//   prep:       out init + vec/wq fp32->bf16 (XCD-aligned vec remap, r7).
//   gemm_3s:    256x128 tile, BK=32, TRIPLE-buffered LDS, distance-2 counted
//               vmcnt (stage kt+2, wait VMCNT(12)), 72 KiB -> 2 blocks/CU.
//               Doubles in-flight DMA vs r0-r8 (Little's law: staging tput
//               was capped by ~6-12 KB in flight x ~2500 cyc latency).
//   syrk_half8: fp8, BK=128, dbuf 2-phase counted-vmcnt, batch->XCD swizzle.
//
// Hard-won constraints (rounds 0-8):
//   - ALL LDS staging via global_load_lds (ds_write staging => 2.26M bank
//     conflicts, -55%; r3).
//   - Dead axes at ~44 us / 28% MfmaUtil: phase count (2/3/4/8), tile shape
//     (128^2/256^2/256x128), wait distance <=1 tile, XCD swizzle, producer
//     alignment, blocks/CU (1 vs 2). (r0-r4, r7, r8)
//   - Intra-block de-sync (no per-tile barrier) hung the container (r5/r6).
//   - relu nonlinear -> syrk K-split across blocks illegal; full K per block.
//   - 16B-granular LDS swizzle: XOR with bits ABOVE the 128B bank period.

typedef short     bf16x8 __attribute__((ext_vector_type(8)));
typedef unsigned short u16x8 __attribute__((ext_vector_type(8)));
typedef float     f32x4 __attribute__((ext_vector_type(4)));
typedef long long i64;

#define FENCE asm volatile("" ::: "memory")
#define BARR  do { FENCE; __builtin_amdgcn_s_barrier(); FENCE; } while (0)
#define VMCNT(N) asm volatile("s_waitcnt vmcnt(" #N ")" ::: "memory")

__device__ inline unsigned short f2bf(float f) {
  unsigned int u = __float_as_uint(f);
  u += 0x7fffu + ((u >> 16) & 1u);   // RNE
  return (unsigned short)(u >> 16);
}

__device__ inline u16x8 pack8(float4 a, float4 b) {
  u16x8 r;
  r[0] = f2bf(a.x); r[1] = f2bf(a.y); r[2] = f2bf(a.z); r[3] = f2bf(a.w);
  r[4] = f2bf(b.x); r[5] = f2bf(b.y); r[6] = f2bf(b.z); r[7] = f2bf(b.w);
  return r;
}

__device__ inline unsigned char f2fp8(float v) {
  int pk = __builtin_amdgcn_cvt_pk_fp8_f32(v, v, 0, false);  // RNE, OCP e4m3
  return (unsigned char)(pk & 0xff);
}

__device__ inline void async16(void* lds, const void* g) {
  __builtin_amdgcn_global_load_lds(
      (const __attribute__((address_space(1))) void*)g,
      (__attribute__((address_space(3))) void*)lds,
      16, 0, 0);
}

// One launch: vec cvt (blocks 0..8191, XCD-aligned), wq cvt, out init.
__global__ __launch_bounds__(256) void prep(
    const float* __restrict__ vec, unsigned short* __restrict__ vecbf,
    const float* __restrict__ wq,  unsigned short* __restrict__ wqbf,
    const float* __restrict__ lin_b, float* __restrict__ out)
{
  if (blockIdx.x < 8192) {
    const int c   = ((blockIdx.x & 7) << 10) + (blockIdx.x >> 3);  // 0..8191
    const int gid = c * 256 + threadIdx.x;
    const float4* s = (const float4*)(vec + (size_t)gid * 8);
    float4 a = s[0], b = s[1];
    *(u16x8*)(vecbf + (size_t)gid * 8) = pack8(a, b);
    const int oid = blockIdx.x * 256 + threadIdx.x;
    if (oid < 8192) out[oid] = lin_b[0];
  } else {
    const int i = (blockIdx.x - 8192) * 256 + threadIdx.x;   // 0..131071
    const float4* s = (const float4*)(wq + (size_t)i * 8);
    float4 a = s[0], b = s[1];
    *(u16x8*)(wqbf + (size_t)i * 8) = pack8(a, b);
  }
}

__global__ void init_out(float* __restrict__ out, const float* __restrict__ lin_b) {
  int i = blockIdx.x * 256 + threadIdx.x;
  if (i < 8192) out[i] = lin_b[0];
}

// ------- gemm_3s: 256x128 tile, BK=32, 3 slots, distance-2 vmcnt -------
// C[m][n] = sum_k A[m][k]*B[n][k];  A=wqbf [1024,1024], B=vecbf [16384,1024].
// 256 thr = 4 waves (2M x 2N); wave tile 128x64 (8x4 16x16 frags).
// LDS: (A 256x32 + B 128x32) bf16 x 3 slots = 72 KiB -> 2 blocks/CU.
// Per K-tile kt: stage(kt+2 -> slot (kt+2)%3) [6 insts]; VMCNT(12) completes
// tile kt (issued 2 iters ago; 18 outstanding -> completes oldest 6);
// BARR; compute slot kt%3; BARR. Keeps 12 loads (2 tiles) in flight at all
// times -- 2x the in-flight DMA of any prior round. Tail drains 12->6->0.
// Slot safety: write slot (kt+2)%3 == read slot (kt-1)%3, whose readers all
// passed the end-of-iter barrier of iter kt-1 before this stage issues.
// Swizzle (r8-proven, 0 conflicts): slot chunk c holds global chunk
// c ^ ((row>>1)&3); fragment read uses quad ^ ((r>>1)&3).
__global__ __launch_bounds__(256, 2) void gemm_3s(
    const unsigned short* __restrict__ A, const unsigned short* __restrict__ Bm,
    const float* __restrict__ bias, unsigned char* __restrict__ qT8)
{
  __shared__ unsigned short As[3][256 * 32];   // 48 KiB
  __shared__ unsigned short Bs[3][128 * 32];   // 24 KiB

  const int n0 = blockIdx.x * 128;   // 128 n-tiles
  const int m0 = blockIdx.y * 256;   // 4 m-tiles

  const int t    = threadIdx.x;          // 0..255
  const int lane = t & 63;
  const int wave = t >> 6;               // 0..3
  const int wm   = (wave >> 1) * 128;    // 0,128
  const int wn   = (wave & 1) * 64;      // 0,64
  const int quad = lane >> 4;
  const int lrow = lane & 15;

  // staging: thread t covers row (t>>2) of each 64-row group, chunk t&3
  // (16 B). Global chunk pre-swizzled: (t&3) ^ ((srow>>1)&3); issue stride
  // 64 rows keeps (row>>1)&3 invariant across p.
  const int srow = t >> 2;                         // 0..63
  const int gch  = (t & 3) ^ ((srow >> 1) & 3);
  const unsigned short* gA = A  + (size_t)(m0 + srow) * 1024 + gch * 8;
  const unsigned short* gB = Bm + (size_t)(n0 + srow) * 1024 + gch * 8;

  // per-thread LDS byte offset within a slot = 16*t  (+ p*4096 B per issue)
#define GSTAGE(SLOT, KT) do { \
  _Pragma("unroll") for (int p = 0; p < 4; ++p) \
    async16(&As[SLOT][p * 2048 + t * 8], gA + (size_t)p * 64 * 1024 + (KT) * 32); \
  _Pragma("unroll") for (int p = 0; p < 2; ++p) \
    async16(&Bs[SLOT][p * 2048 + t * 8], gB + (size_t)p * 64 * 1024 + (KT) * 32); \
} while (0)

  // fragment read: row r, want global chunk=quad -> slot quad ^ ((r>>1)&3)
#define GCOMPUTE(S) do { \
  bf16x8 af[8], bfr[4]; \
  _Pragma("unroll") for (int f = 0; f < 8; ++f) { \
    const int r = wm + f * 16 + lrow; \
    af[f] = *(const bf16x8*)&As[S][r * 32 + ((quad ^ ((r >> 1) & 3)) * 8)]; \
  } \
  _Pragma("unroll") for (int g = 0; g < 4; ++g) { \
    const int r = wn + g * 16 + lrow; \
    bfr[g] = *(const bf16x8*)&Bs[S][r * 32 + ((quad ^ ((r >> 1) & 3)) * 8)]; \
  } \
  __builtin_amdgcn_s_setprio(1); \
  _Pragma("unroll") for (int f = 0; f < 8; ++f) \
  _Pragma("unroll") for (int g = 0; g < 4; ++g) \
    acc[f][g] = __builtin_amdgcn_mfma_f32_16x16x32_bf16(af[f], bfr[g], acc[f][g], 0, 0, 0); \
  __builtin_amdgcn_s_setprio(0); \
} while (0)

  f32x4 acc[8][4];
#pragma unroll
  for (int f = 0; f < 8; ++f)
#pragma unroll
    for (int g = 0; g < 4; ++g) acc[f][g] = (f32x4){0.f, 0.f, 0.f, 0.f};

  // prologue: stage tiles 0,1 -> slots 0,1 (12 insts outstanding)
  GSTAGE(0, 0);
  GSTAGE(1, 1);

  int srd = 0;   // read slot  (kt % 3)
  int sst = 2;   // stage slot ((kt+2) % 3)

#pragma unroll 1
  for (int kt = 0; kt < 30; ++kt) {
    GSTAGE(sst, kt + 2);     // 18 outstanding (tiles kt, kt+1, kt+2)
    VMCNT(12);               // completes tile kt; keeps 12 (2 tiles) in flight
    BARR;                    // all waves' tile-kt stages now visible
    GCOMPUTE(srd);
    BARR;                    // reads done before next iter overwrites slot
    srd = (srd == 2) ? 0 : srd + 1;
    sst = (sst == 2) ? 0 : sst + 1;
  }

  // kt=30: outstanding 12 (tiles 30,31)
  VMCNT(6);                  // tile 30 resident, tile 31 in flight
  BARR;
  GCOMPUTE(0);               // 30 % 3 == 0
  BARR;

  // kt=31: drain
  VMCNT(0);
  BARR;
  GCOMPUTE(1);               // 31 % 3 == 1

#undef GSTAGE
#undef GCOMPUTE

  // ---- epilogue: bias + fp8 quantize, write qT8[m][n] ----
#pragma unroll
  for (int f = 0; f < 8; ++f)
#pragma unroll
    for (int r = 0; r < 4; ++r) {
      const int m = m0 + wm + f * 16 + quad * 4 + r;
      const float bv = bias[m];
      unsigned char* row = qT8 + (size_t)m * 16384 + n0 + wn;
#pragma unroll
      for (int g = 0; g < 4; ++g)
        row[g * 16 + lrow] = f2fp8(acc[f][g][r] + bv);
    }
}

// ------- fallback gemm_q (fused fp32->bf16 inline), used if ws too small -------
__global__ __launch_bounds__(256) void gemm_q_fused(
    const float* __restrict__ Wq, const float* __restrict__ V,
    const float* __restrict__ bias, unsigned char* __restrict__ qT8)
{
  __shared__ unsigned short As[128 * 32];
  __shared__ unsigned short Bs[128 * 32];

  const int m0 = blockIdx.y * 128;
  const int n0 = blockIdx.x * 128;
  const int t    = threadIdx.x;
  const int lane = t & 63;
  const int wave = t >> 6;
  const int wm = (wave >> 1) * 64;
  const int wn = (wave & 1) * 64;
  const int quad = lane >> 4;
  const int lrow = lane & 15;

  const int sr = t >> 1;
  const int sc = (t & 1) << 4;
  const float* gA = Wq + (size_t)(m0 + sr) * 1024 + sc;
  const float* gB = V  + (size_t)(n0 + sr) * 1024 + sc;

  f32x4 acc[4][4];
#pragma unroll
  for (int i = 0; i < 4; ++i)
#pragma unroll
    for (int j = 0; j < 4; ++j) acc[i][j] = (f32x4){0.f, 0.f, 0.f, 0.f};

  for (int k0 = 0; k0 < 1024; k0 += 32) {
    const float4* a4 = (const float4*)(gA + k0);
    const float4* b4 = (const float4*)(gB + k0);
    float4 av0 = a4[0], av1 = a4[1], av2 = a4[2], av3 = a4[3];
    float4 bv0 = b4[0], bv1 = b4[1], bv2 = b4[2], bv3 = b4[3];
    *(u16x8*)&As[sr * 32 + sc]     = pack8(av0, av1);
    *(u16x8*)&As[sr * 32 + sc + 8] = pack8(av2, av3);
    *(u16x8*)&Bs[sr * 32 + sc]     = pack8(bv0, bv1);
    *(u16x8*)&Bs[sr * 32 + sc + 8] = pack8(bv2, bv3);
    __syncthreads();

    bf16x8 af[4], bfr[4];
#pragma unroll
    for (int i = 0; i < 4; ++i)
      af[i] = *(const bf16x8*)&As[(wm + i * 16 + lrow) * 32 + quad * 8];
#pragma unroll
    for (int j = 0; j < 4; ++j)
      bfr[j] = *(const bf16x8*)&Bs[(wn + j * 16 + lrow) * 32 + quad * 8];
#pragma unroll
    for (int i = 0; i < 4; ++i)
#pragma unroll
      for (int j = 0; j < 4; ++j)
        acc[i][j] = __builtin_amdgcn_mfma_f32_16x16x32_bf16(af[i], bfr[j], acc[i][j], 0, 0, 0);
    __syncthreads();
  }

#pragma unroll
  for (int i = 0; i < 4; ++i) {
    const int mb = m0 + wm + i * 16 + quad * 4;
#pragma unroll
    for (int r = 0; r < 4; ++r) {
      const float bv = bias[mb + r];
#pragma unroll
      for (int j = 0; j < 4; ++j) {
        const int n = n0 + wn + j * 16 + lrow;
        qT8[(size_t)(mb + r) * 16384 + n] = f2fp8(acc[i][j][r] + bv);
      }
    }
  }
}

// ---------- syrk_half8: fp8, BK=128, dbuf 2-phase, batch->XCD swizzle ----------
// qT8 fp8 [1024][16384]; batch bb cols [bb*2048,+2048) = 2 MiB -> fits ONE
// XCD's 4 MiB L2. blockIdx.x in [0,576): bb = bid&7 so all 72 blocks of batch
// bb land on XCD bb -> after warmup all qT8 reads are L2 hits.
// id2=bid>>3: pair=id2>>1 (ty<=tx over 8 128-tiles), yh=id2&1.
// FULL K=2048 (relu nonlinear -> K-split illegal).
__global__ __launch_bounds__(256) void syrk_half8(
    const unsigned char* __restrict__ qT8, const float* __restrict__ W,
    float* __restrict__ out)
{
  __shared__ unsigned char As[2][128 * 128];  // 32 KB
  __shared__ unsigned char Bs[2][64 * 128];   // 16 KB

  const int bb   = blockIdx.x & 7;
  const int id2  = blockIdx.x >> 3;           // 0..71
  const int pair = id2 >> 1;
  const int yh   = id2 & 1;
  int tx = 0;
  while ((tx + 1) * (tx + 2) / 2 <= pair) ++tx;
  const int ty = pair - tx * (tx + 1) / 2;
  const int x0 = tx * 128;
  const int y0 = ty * 128 + yh * 64;
  const bool diag = (tx == ty);

  const int t    = threadIdx.x;
  const int lane = t & 63;
  const int wave = t >> 6;
  const int wm = (wave >> 1) * 64;   // x offset of wave: 0 or 64
  const int wn = (wave & 1) * 32;    // y offset of wave: 0 or 32
  const int quad = lane >> 4;
  const int lrow = lane & 15;

  // staging: issue p covers rows p*32 + (t>>3); global 16B chunk
  // (t&7)^(row&7) lands at LDS slot t&7.
  const int srow = t >> 3;                              // 0..31
  const int g16  = (t & 7) ^ (srow & 7);
  const size_t cb = (size_t)bb * 2048 + g16 * 16;
  const unsigned char* gA = qT8 + (size_t)(x0 + srow) * 16384 + cb;
  const unsigned char* gB = qT8 + (size_t)(y0 + srow) * 16384 + cb;

#define SSTAGE(SLOT, KT) do { \
  _Pragma("unroll") for (int p = 0; p < 4; ++p) \
    async16(&As[SLOT][p * 4096 + t * 16], gA + (size_t)p * 32 * 16384 + (KT) * 128); \
  _Pragma("unroll") for (int p = 0; p < 2; ++p) \
    async16(&Bs[SLOT][p * 4096 + t * 16], gB + (size_t)p * 32 * 16384 + (KT) * 128); \
} while (0)

#define SYRK_COMPUTE(S) do { \
  _Pragma("unroll") for (int kk = 0; kk < 4; ++kk) { \
    const int c = kk * 4 + quad; \
    const int off = (((c >> 1) ^ (lrow & 7)) << 4) + (c & 1) * 8; \
    i64 af[4], bfr[2]; \
    _Pragma("unroll") for (int i = 0; i < 4; ++i) \
      af[i] = *(const i64*)&As[S][(wm + i * 16 + lrow) * 128 + off]; \
    _Pragma("unroll") for (int j = 0; j < 2; ++j) \
      bfr[j] = *(const i64*)&Bs[S][(wn + j * 16 + lrow) * 128 + off]; \
    _Pragma("unroll") for (int i = 0; i < 4; ++i) \
      _Pragma("unroll") for (int j = 0; j < 2; ++j) \
        acc[i][j] = __builtin_amdgcn_mfma_f32_16x16x32_fp8_fp8(af[i], bfr[j], acc[i][j], 0, 0, 0); \
  } \
} while (0)

  f32x4 acc[4][2];
#pragma unroll
  for (int i = 0; i < 4; ++i)
#pragma unroll
    for (int j = 0; j < 2; ++j) acc[i][j] = (f32x4){0.f, 0.f, 0.f, 0.f};

  // prologue: stage tile 0 -> slot 0 (6 insts outstanding)
  SSTAGE(0, 0);

#pragma unroll 1
  for (int kt = 0; kt < 15; ++kt) {
    const int s = kt & 1;
    SSTAGE(s ^ 1, kt + 1);   // 6 insts; tile t's 6 may still be in flight
    VMCNT(6);                // completes tile t, leaves tile t+1 in flight
    BARR;                    // all waves' tile-t stages now visible
    SYRK_COMPUTE(s);
    BARR;                    // reads done before next iter overwrites slot s
  }

  // peeled kt=15 (slot 1): drain
  VMCNT(0);
  BARR;
  SYRK_COMPUTE(1);

#undef SSTAGE
#undef SYRK_COMPUTE

  float* ob = out + bb * 1024;

  // row pass: out[x] += sum_y relu(C[x,y]) * W[y]   (partial over this y-half)
  float wv[2];
#pragma unroll
  for (int j = 0; j < 2; ++j) wv[j] = W[y0 + wn + j * 16 + lrow];

#pragma unroll
  for (int i = 0; i < 4; ++i) {
#pragma unroll
    for (int r = 0; r < 4; ++r) {
      float p = 0.f;
#pragma unroll
      for (int j = 0; j < 2; ++j) {
        float v = acc[i][j][r];
        v = v > 0.f ? v : 0.f;
        p += v * wv[j];
      }
#pragma unroll
      for (int off = 1; off < 16; off <<= 1) p += __shfl_xor(p, off, 64);
      if (lrow == 0)
        atomicAdd(&ob[x0 + wm + i * 16 + quad * 4 + r], p);
    }
  }

  // col pass (off-diagonal pairs only): out[y] += sum_x relu(C[x,y]) * W[x]
  if (!diag) {
    float wx[4][4];
#pragma unroll
    for (int i = 0; i < 4; ++i)
#pragma unroll
      for (int r = 0; r < 4; ++r)
        wx[i][r] = W[x0 + wm + i * 16 + quad * 4 + r];

#pragma unroll
    for (int j = 0; j < 2; ++j) {
      float pc = 0.f;
#pragma unroll
      for (int i = 0; i < 4; ++i)
#pragma unroll
        for (int r = 0; r < 4; ++r) {
          float v = acc[i][j][r];
          v = v > 0.f ? v : 0.f;
          pc += v * wx[i][r];
        }
      pc += __shfl_xor(pc, 16, 64);
      pc += __shfl_xor(pc, 32, 64);
      if (quad == 0)
        atomicAdd(&ob[y0 + wn + j * 16 + lrow], pc);
    }
  }
}

extern "C" void kernel_launch(void* const* d_in, const int* in_sizes, int n_in,
                              void* d_out, int out_size, void* d_ws, size_t ws_size,
                              hipStream_t stream) {
  const float* vec   = (const float*)d_in[0];  // [8,2048,1024]
  const float* wq_w  = (const float*)d_in[1];  // [1024,1024]
  const float* wq_b  = (const float*)d_in[2];  // [1024]
  const float* lin_w = (const float*)d_in[3];  // [1,1024]
  const float* lin_b = (const float*)d_in[4];  // [1]
  float* out = (float*)d_out;                  // [8,1024]

  unsigned char* qT8 = (unsigned char*)d_ws;                       // 16 MiB
  const size_t need = (size_t)(16 + 32 + 2) * 1024 * 1024;

  if (ws_size >= need) {
    unsigned short* vecbf = (unsigned short*)((char*)d_ws + (size_t)16 * 1024 * 1024); // 32 MiB
    unsigned short* wqbf  = vecbf + (size_t)16 * 1024 * 1024;                          // 2 MiB
    prep<<<dim3(8192 + 512), dim3(256), 0, stream>>>(vec, vecbf, wq_w, wqbf, lin_b, out);
    gemm_3s<<<dim3(128, 4), dim3(256), 0, stream>>>(wqbf, vecbf, wq_b, qT8);
  } else {
    init_out<<<dim3(32), dim3(256), 0, stream>>>(out, lin_b);
    gemm_q_fused<<<dim3(128, 8), dim3(256), 0, stream>>>(wq_w, vec, wq_b, qT8);
  }
  syrk_half8<<<dim3(576), dim3(256), 0, stream>>>(qT8, lin_w, out);
}

// Round 10
// 163.795 us; speedup vs baseline: 1.0144x; 1.0110x over previous
//
#include <hip/hip_runtime.h>

// B=8, S=2048, IN=1024, H=1024
//   q  = vec @ wq_w^T + wq_b            [B,S,H]
//   ret= relu(q_b^T q_b) per batch      [B,H,H]   (registers only)
//   out= ret @ lin_w + lin_b            [B,H]
//
// Pipeline:
//   prep:       out init + vec/wq fp32->bf16 (XCD-aligned vec remap, r7).
//   gemm_1p:    256x256 tile, BK=64, ONE compute phase per K-tile (2 barriers)
//               -> 16 barrier-pairs/CU, 4x fewer than all prior variants.
//               Empirical law from r0-r9: ~1650 cyc per barrier-pair
//               regardless of the work inside; every prior variant had 64
//               pairs/CU and every one measured ~44 us.
//   syrk_half8: fp8, BK=128, dbuf 2-phase counted-vmcnt, batch->XCD swizzle.
//
// Hard-won constraints (rounds 0-9):
//   - ALL LDS staging via global_load_lds (ds_write staging => 2.26M bank
//     conflicts, -55%; r3).
//   - Dead axes at ~44 us: phase count at fixed pairs/CU, tile shape, wait
//     distance 1 tile, XCD swizzle, producer alignment, blocks/CU (r0-r8).
//   - Distance-2 (18 outstanding) REGRESSES to 52 us (r9).
//   - Intra-block de-sync (no per-tile barrier) hung the container (r5/r6).
//   - relu nonlinear -> syrk K-split across blocks illegal; full K per block.

typedef short     bf16x8 __attribute__((ext_vector_type(8)));
typedef unsigned short u16x8 __attribute__((ext_vector_type(8)));
typedef float     f32x4 __attribute__((ext_vector_type(4)));
typedef long long i64;

#define FENCE asm volatile("" ::: "memory")
#define BARR  do { FENCE; __builtin_amdgcn_s_barrier(); FENCE; } while (0)
#define VMCNT(N) asm volatile("s_waitcnt vmcnt(" #N ")" ::: "memory")

__device__ inline unsigned short f2bf(float f) {
  unsigned int u = __float_as_uint(f);
  u += 0x7fffu + ((u >> 16) & 1u);   // RNE
  return (unsigned short)(u >> 16);
}

__device__ inline u16x8 pack8(float4 a, float4 b) {
  u16x8 r;
  r[0] = f2bf(a.x); r[1] = f2bf(a.y); r[2] = f2bf(a.z); r[3] = f2bf(a.w);
  r[4] = f2bf(b.x); r[5] = f2bf(b.y); r[6] = f2bf(b.z); r[7] = f2bf(b.w);
  return r;
}

__device__ inline unsigned char f2fp8(float v) {
  int pk = __builtin_amdgcn_cvt_pk_fp8_f32(v, v, 0, false);  // RNE, OCP e4m3
  return (unsigned char)(pk & 0xff);
}

__device__ inline void async16(void* lds, const void* g) {
  __builtin_amdgcn_global_load_lds(
      (const __attribute__((address_space(1))) void*)g,
      (__attribute__((address_space(3))) void*)lds,
      16, 0, 0);
}

// One launch: vec cvt (blocks 0..8191, XCD-aligned), wq cvt, out init.
__global__ __launch_bounds__(256) void prep(
    const float* __restrict__ vec, unsigned short* __restrict__ vecbf,
    const float* __restrict__ wq,  unsigned short* __restrict__ wqbf,
    const float* __restrict__ lin_b, float* __restrict__ out)
{
  if (blockIdx.x < 8192) {
    const int c   = ((blockIdx.x & 7) << 10) + (blockIdx.x >> 3);  // 0..8191
    const int gid = c * 256 + threadIdx.x;
    const float4* s = (const float4*)(vec + (size_t)gid * 8);
    float4 a = s[0], b = s[1];
    *(u16x8*)(vecbf + (size_t)gid * 8) = pack8(a, b);
    const int oid = blockIdx.x * 256 + threadIdx.x;
    if (oid < 8192) out[oid] = lin_b[0];
  } else {
    const int i = (blockIdx.x - 8192) * 256 + threadIdx.x;   // 0..131071
    const float4* s = (const float4*)(wq + (size_t)i * 8);
    float4 a = s[0], b = s[1];
    *(u16x8*)(wqbf + (size_t)i * 8) = pack8(a, b);
  }
}

__global__ void init_out(float* __restrict__ out, const float* __restrict__ lin_b) {
  int i = blockIdx.x * 256 + threadIdx.x;
  if (i < 8192) out[i] = lin_b[0];
}

// ------- gemm_1p: 256x256 tile, BK=64, ONE compute phase per K-tile -------
// C[m][n] = sum_k A[m][k]*B[n][k];  A=wqbf [1024,1024], B=vecbf [16384,1024].
// 512 thr = 8 waves (2M x 4N).  LDS = 2 slots x (A 32K + B 32K) = 128 KiB,
// 1 block/CU, 256 blocks. Per K-tile: stage tile kt+1 (8 insts) -> VMCNT(8)
// (completes tile kt, leaves kt+1 in flight) -> BARR -> 24 ds_reads + 64 MFMA
// -> BARR. 16 barrier-pairs per CU total (vs 64 in r0/r1/r4/r8).
// Geometry, staging pattern, swizzle, epilogue identical to r4's gemm_q8p.
__global__ __launch_bounds__(512, 2) void gemm_1p(
    const unsigned short* __restrict__ A, const unsigned short* __restrict__ Bm,
    const float* __restrict__ bias, unsigned char* __restrict__ qT8)
{
  __shared__ unsigned short As[2][256 * 64];   // 64 KiB
  __shared__ unsigned short Bs[2][256 * 64];   // 64 KiB

  // bijective XCD remap (256 = 8 XCD x 32)
  const int bid = blockIdx.y * 64 + blockIdx.x;   // 0..255
  const int xcd = bid & 7;
  const int idx = bid >> 3;                       // 0..31
  const int m0 = (idx & 3) * 256;                 // 4 M-tiles
  const int n0 = (xcd * 8 + (idx >> 2)) * 256;    // 64 N-tiles, chunked per XCD

  const int t    = threadIdx.x;          // 0..511
  const int lane = t & 63;
  const int wave = t >> 6;               // 0..7
  const int wm2  = (wave >> 2) * 64;     // 0,64
  const int wn2  = (wave & 3) * 32;      // 0..96
  const int quad = lane >> 4;
  const int lrow = lane & 15;

  // staging: thread t covers row (t>>3) of each 64-row group, LDS 16B slot t&7;
  // pre-swizzled global chunk (t&7)^(row&7) so ds_read applies the same XOR.
  const int srow = t >> 3;                         // 0..63
  const int gch  = (t & 7) ^ (srow & 7);
  const unsigned short* gA = A  + (size_t)(m0 + srow) * 1024 + gch * 8;
  const unsigned short* gB = Bm + (size_t)(n0 + srow) * 1024 + gch * 8;

#define STAGE_A(SLOT, H, KT) do { \
  _Pragma("unroll") for (int p = 0; p < 2; ++p) \
    async16(&As[SLOT][((H)*128 + p*64)*64 + t*8], \
            gA + (size_t)((H)*128 + p*64)*1024 + (KT)*64); \
} while (0)

#define STAGE_B(SLOT, H, KT) do { \
  _Pragma("unroll") for (int p = 0; p < 2; ++p) \
    async16(&Bs[SLOT][((H)*128 + p*64)*64 + t*8], \
            gB + (size_t)((H)*128 + p*64)*1024 + (KT)*64); \
} while (0)

#define LDA_HALF(S, MH) do { \
  _Pragma("unroll") for (int f = 0; f < 4; ++f) \
  _Pragma("unroll") for (int kk = 0; kk < 2; ++kk) \
    a_[f][kk] = *(const bf16x8*)&As[S][((MH)*128 + wm2 + f*16 + lrow)*64 + \
                                       (((kk*4 + quad) ^ (lrow & 7)) * 8)]; \
} while (0)

#define LDB_HALF(S, NH, BREG) do { \
  _Pragma("unroll") for (int g = 0; g < 2; ++g) \
  _Pragma("unroll") for (int kk = 0; kk < 2; ++kk) \
    BREG[g][kk] = *(const bf16x8*)&Bs[S][((NH)*128 + wn2 + g*16 + lrow)*64 + \
                                         (((kk*4 + quad) ^ (lrow & 7)) * 8)]; \
} while (0)

#define MFMAQ(MH, NH, BREG) do { \
  __builtin_amdgcn_s_setprio(1); \
  _Pragma("unroll") for (int kk = 0; kk < 2; ++kk) \
  _Pragma("unroll") for (int f = 0; f < 4; ++f) \
  _Pragma("unroll") for (int g = 0; g < 2; ++g) \
    acc[MH][f][NH][g] = __builtin_amdgcn_mfma_f32_16x16x32_bf16( \
        a_[f][kk], BREG[g][kk], acc[MH][f][NH][g], 0, 0, 0); \
  __builtin_amdgcn_s_setprio(0); \
} while (0)

  f32x4 acc[2][4][2][2];
#pragma unroll
  for (int i = 0; i < 2; ++i)
#pragma unroll
    for (int f = 0; f < 4; ++f)
#pragma unroll
      for (int j = 0; j < 2; ++j)
#pragma unroll
        for (int g = 0; g < 2; ++g) acc[i][f][j][g] = (f32x4){0.f, 0.f, 0.f, 0.f};

  bf16x8 a_[4][2], b0_[2][2], b1_[2][2];

  // ---- prologue: tile 0 -> slot 0 (8 insts outstanding) ----
  STAGE_A(0, 0, 0);
  STAGE_B(0, 0, 0);
  STAGE_A(0, 1, 0);
  STAGE_B(0, 1, 0);

  // ---- main loop: ONE barrier-pair per K-tile ----
#pragma unroll 1
  for (int kt = 0; kt < 15; ++kt) {
    const int s  = kt & 1;
    const int so = s ^ 1;

    // stage tile kt+1 into the other slot (its prior readers finished at
    // iter kt-1's closing barrier); 16 outstanding after these 8.
    STAGE_A(so, 0, kt + 1);
    STAGE_B(so, 0, kt + 1);
    STAGE_A(so, 1, kt + 1);
    STAGE_B(so, 1, kt + 1);
    VMCNT(8);              // completes tile kt; tile kt+1 stays in flight
    BARR;                  // all waves' tile-kt DMAs visible

    LDA_HALF(s, 0);
    LDB_HALF(s, 0, b0_);
    MFMAQ(0, 0, b0_);
    LDB_HALF(s, 1, b1_);
    MFMAQ(0, 1, b1_);
    LDA_HALF(s, 1);
    MFMAQ(1, 0, b0_);
    MFMAQ(1, 1, b1_);
    BARR;                  // reads done before next iter overwrites slot s^1
  }

  // ---- peeled tile 15 (slot 1): drain ----
  VMCNT(0);
  BARR;
  LDA_HALF(1, 0);
  LDB_HALF(1, 0, b0_);
  MFMAQ(0, 0, b0_);
  LDB_HALF(1, 1, b1_);
  MFMAQ(0, 1, b1_);
  LDA_HALF(1, 1);
  MFMAQ(1, 0, b0_);
  MFMAQ(1, 1, b1_);

  // ---- epilogue: bias + fp8 quantize, write qT8[m][n] ----
#pragma unroll
  for (int mh = 0; mh < 2; ++mh)
#pragma unroll
    for (int f = 0; f < 4; ++f)
#pragma unroll
      for (int r = 0; r < 4; ++r) {
        const int m = m0 + mh * 128 + wm2 + f * 16 + quad * 4 + r;
        const float bv = bias[m];
        unsigned char* row = qT8 + (size_t)m * 16384 + n0;
#pragma unroll
        for (int nh = 0; nh < 2; ++nh)
#pragma unroll
          for (int g = 0; g < 2; ++g)
            row[nh * 128 + wn2 + g * 16 + lrow] = f2fp8(acc[mh][f][nh][g][r] + bv);
      }

#undef STAGE_A
#undef STAGE_B
#undef LDA_HALF
#undef LDB_HALF
#undef MFMAQ
}

// ------- fallback gemm_q (fused fp32->bf16 inline), used if ws too small -------
__global__ __launch_bounds__(256) void gemm_q_fused(
    const float* __restrict__ Wq, const float* __restrict__ V,
    const float* __restrict__ bias, unsigned char* __restrict__ qT8)
{
  __shared__ unsigned short As[128 * 32];
  __shared__ unsigned short Bs[128 * 32];

  const int m0 = blockIdx.y * 128;
  const int n0 = blockIdx.x * 128;
  const int t    = threadIdx.x;
  const int lane = t & 63;
  const int wave = t >> 6;
  const int wm = (wave >> 1) * 64;
  const int wn = (wave & 1) * 64;
  const int quad = lane >> 4;
  const int lrow = lane & 15;

  const int sr = t >> 1;
  const int sc = (t & 1) << 4;
  const float* gA = Wq + (size_t)(m0 + sr) * 1024 + sc;
  const float* gB = V  + (size_t)(n0 + sr) * 1024 + sc;

  f32x4 acc[4][4];
#pragma unroll
  for (int i = 0; i < 4; ++i)
#pragma unroll
    for (int j = 0; j < 4; ++j) acc[i][j] = (f32x4){0.f, 0.f, 0.f, 0.f};

  for (int k0 = 0; k0 < 1024; k0 += 32) {
    const float4* a4 = (const float4*)(gA + k0);
    const float4* b4 = (const float4*)(gB + k0);
    float4 av0 = a4[0], av1 = a4[1], av2 = a4[2], av3 = a4[3];
    float4 bv0 = b4[0], bv1 = b4[1], bv2 = b4[2], bv3 = b4[3];
    *(u16x8*)&As[sr * 32 + sc]     = pack8(av0, av1);
    *(u16x8*)&As[sr * 32 + sc + 8] = pack8(av2, av3);
    *(u16x8*)&Bs[sr * 32 + sc]     = pack8(bv0, bv1);
    *(u16x8*)&Bs[sr * 32 + sc + 8] = pack8(bv2, bv3);
    __syncthreads();

    bf16x8 af[4], bfr[4];
#pragma unroll
    for (int i = 0; i < 4; ++i)
      af[i] = *(const bf16x8*)&As[(wm + i * 16 + lrow) * 32 + quad * 8];
#pragma unroll
    for (int j = 0; j < 4; ++j)
      bfr[j] = *(const bf16x8*)&Bs[(wn + j * 16 + lrow) * 32 + quad * 8];
#pragma unroll
    for (int i = 0; i < 4; ++i)
#pragma unroll
      for (int j = 0; j < 4; ++j)
        acc[i][j] = __builtin_amdgcn_mfma_f32_16x16x32_bf16(af[i], bfr[j], acc[i][j], 0, 0, 0);
    __syncthreads();
  }

#pragma unroll
  for (int i = 0; i < 4; ++i) {
    const int mb = m0 + wm + i * 16 + quad * 4;
#pragma unroll
    for (int r = 0; r < 4; ++r) {
      const float bv = bias[mb + r];
#pragma unroll
      for (int j = 0; j < 4; ++j) {
        const int n = n0 + wn + j * 16 + lrow;
        qT8[(size_t)(mb + r) * 16384 + n] = f2fp8(acc[i][j][r] + bv);
      }
    }
  }
}

// ---------- syrk_half8: fp8, BK=128, dbuf 2-phase, batch->XCD swizzle ----------
// qT8 fp8 [1024][16384]; batch bb cols [bb*2048,+2048) = 2 MiB -> fits ONE
// XCD's 4 MiB L2. blockIdx.x in [0,576): bb = bid&7 so all 72 blocks of batch
// bb land on XCD bb -> after warmup all qT8 reads are L2 hits.
// id2=bid>>3: pair=id2>>1 (ty<=tx over 8 128-tiles), yh=id2&1.
// FULL K=2048 (relu nonlinear -> K-split illegal).
__global__ __launch_bounds__(256) void syrk_half8(
    const unsigned char* __restrict__ qT8, const float* __restrict__ W,
    float* __restrict__ out)
{
  __shared__ unsigned char As[2][128 * 128];  // 32 KB
  __shared__ unsigned char Bs[2][64 * 128];   // 16 KB

  const int bb   = blockIdx.x & 7;
  const int id2  = blockIdx.x >> 3;           // 0..71
  const int pair = id2 >> 1;
  const int yh   = id2 & 1;
  int tx = 0;
  while ((tx + 1) * (tx + 2) / 2 <= pair) ++tx;
  const int ty = pair - tx * (tx + 1) / 2;
  const int x0 = tx * 128;
  const int y0 = ty * 128 + yh * 64;
  const bool diag = (tx == ty);

  const int t    = threadIdx.x;
  const int lane = t & 63;
  const int wave = t >> 6;
  const int wm = (wave >> 1) * 64;   // x offset of wave: 0 or 64
  const int wn = (wave & 1) * 32;    // y offset of wave: 0 or 32
  const int quad = lane >> 4;
  const int lrow = lane & 15;

  // staging: issue p covers rows p*32 + (t>>3); global 16B chunk
  // (t&7)^(row&7) lands at LDS slot t&7.
  const int srow = t >> 3;                              // 0..31
  const int g16  = (t & 7) ^ (srow & 7);
  const size_t cb = (size_t)bb * 2048 + g16 * 16;
  const unsigned char* gA = qT8 + (size_t)(x0 + srow) * 16384 + cb;
  const unsigned char* gB = qT8 + (size_t)(y0 + srow) * 16384 + cb;

#define SSTAGE(SLOT, KT) do { \
  _Pragma("unroll") for (int p = 0; p < 4; ++p) \
    async16(&As[SLOT][p * 4096 + t * 16], gA + (size_t)p * 32 * 16384 + (KT) * 128); \
  _Pragma("unroll") for (int p = 0; p < 2; ++p) \
    async16(&Bs[SLOT][p * 4096 + t * 16], gB + (size_t)p * 32 * 16384 + (KT) * 128); \
} while (0)

#define SYRK_COMPUTE(S) do { \
  _Pragma("unroll") for (int kk = 0; kk < 4; ++kk) { \
    const int c = kk * 4 + quad; \
    const int off = (((c >> 1) ^ (lrow & 7)) << 4) + (c & 1) * 8; \
    i64 af[4], bfr[2]; \
    _Pragma("unroll") for (int i = 0; i < 4; ++i) \
      af[i] = *(const i64*)&As[S][(wm + i * 16 + lrow) * 128 + off]; \
    _Pragma("unroll") for (int j = 0; j < 2; ++j) \
      bfr[j] = *(const i64*)&Bs[S][(wn + j * 16 + lrow) * 128 + off]; \
    _Pragma("unroll") for (int i = 0; i < 4; ++i) \
      _Pragma("unroll") for (int j = 0; j < 2; ++j) \
        acc[i][j] = __builtin_amdgcn_mfma_f32_16x16x32_fp8_fp8(af[i], bfr[j], acc[i][j], 0, 0, 0); \
  } \
} while (0)

  f32x4 acc[4][2];
#pragma unroll
  for (int i = 0; i < 4; ++i)
#pragma unroll
    for (int j = 0; j < 2; ++j) acc[i][j] = (f32x4){0.f, 0.f, 0.f, 0.f};

  // prologue: stage tile 0 -> slot 0 (6 insts outstanding)
  SSTAGE(0, 0);

#pragma unroll 1
  for (int kt = 0; kt < 15; ++kt) {
    const int s = kt & 1;
    SSTAGE(s ^ 1, kt + 1);   // 6 insts; tile t's 6 may still be in flight
    VMCNT(6);                // completes tile t, leaves tile t+1 in flight
    BARR;                    // all waves' tile-t stages now visible
    SYRK_COMPUTE(s);
    BARR;                    // reads done before next iter overwrites slot s
  }

  // peeled kt=15 (slot 1): drain
  VMCNT(0);
  BARR;
  SYRK_COMPUTE(1);

#undef SSTAGE
#undef SYRK_COMPUTE

  float* ob = out + bb * 1024;

  // row pass: out[x] += sum_y relu(C[x,y]) * W[y]   (partial over this y-half)
  float wv[2];
#pragma unroll
  for (int j = 0; j < 2; ++j) wv[j] = W[y0 + wn + j * 16 + lrow];

#pragma unroll
  for (int i = 0; i < 4; ++i) {
#pragma unroll
    for (int r = 0; r < 4; ++r) {
      float p = 0.f;
#pragma unroll
      for (int j = 0; j < 2; ++j) {
        float v = acc[i][j][r];
        v = v > 0.f ? v : 0.f;
        p += v * wv[j];
      }
#pragma unroll
      for (int off = 1; off < 16; off <<= 1) p += __shfl_xor(p, off, 64);
      if (lrow == 0)
        atomicAdd(&ob[x0 + wm + i * 16 + quad * 4 + r], p);
    }
  }

  // col pass (off-diagonal pairs only): out[y] += sum_x relu(C[x,y]) * W[x]
  if (!diag) {
    float wx[4][4];
#pragma unroll
    for (int i = 0; i < 4; ++i)
#pragma unroll
      for (int r = 0; r < 4; ++r)
        wx[i][r] = W[x0 + wm + i * 16 + quad * 4 + r];

#pragma unroll
    for (int j = 0; j < 2; ++j) {
      float pc = 0.f;
#pragma unroll
      for (int i = 0; i < 4; ++i)
#pragma unroll
        for (int r = 0; r < 4; ++r) {
          float v = acc[i][j][r];
          v = v > 0.f ? v : 0.f;
          pc += v * wx[i][r];
        }
      pc += __shfl_xor(pc, 16, 64);
      pc += __shfl_xor(pc, 32, 64);
      if (quad == 0)
        atomicAdd(&ob[y0 + wn + j * 16 + lrow], pc);
    }
  }
}

extern "C" void kernel_launch(void* const* d_in, const int* in_sizes, int n_in,
                              void* d_out, int out_size, void* d_ws, size_t ws_size,
                              hipStream_t stream) {
  const float* vec   = (const float*)d_in[0];  // [8,2048,1024]
  const float* wq_w  = (const float*)d_in[1];  // [1024,1024]
  const float* wq_b  = (const float*)d_in[2];  // [1024]
  const float* lin_w = (const float*)d_in[3];  // [1,1024]
  const float* lin_b = (const float*)d_in[4];  // [1]
  float* out = (float*)d_out;                  // [8,1024]

  unsigned char* qT8 = (unsigned char*)d_ws;                       // 16 MiB
  const size_t need = (size_t)(16 + 32 + 2) * 1024 * 1024;

  if (ws_size >= need) {
    unsigned short* vecbf = (unsigned short*)((char*)d_ws + (size_t)16 * 1024 * 1024); // 32 MiB
    unsigned short* wqbf  = vecbf + (size_t)16 * 1024 * 1024;                          // 2 MiB
    prep<<<dim3(8192 + 512), dim3(256), 0, stream>>>(vec, vecbf, wq_w, wqbf, lin_b, out);
    gemm_1p<<<dim3(64, 4), dim3(512), 0, stream>>>(wqbf, vecbf, wq_b, qT8);
  } else {
    init_out<<<dim3(32), dim3(256), 0, stream>>>(out, lin_b);
    gemm_q_fused<<<dim3(128, 8), dim3(256), 0, stream>>>(wq_w, vec, wq_b, qT8);
  }
  syrk_half8<<<dim3(576), dim3(256), 0, stream>>>(qT8, lin_w, out);
}